// Round 7
// baseline (412.810 us; speedup 1.0000x reference)
//
#include <hip/hip_runtime.h>

// B,H,N,D,E = 2,8,512,16,128
constexpr int CB = 2;
constexpr int CH = 8;
constexpr int CN = 512;
constexpr int CD = 16;
constexpr int CE = 128;
constexpr int CHD = CH * CD;   // 128
constexpr int TM = 32;         // m-rows per z tile
constexpr int NTILE = CN / TM; // 16
constexpr int NT = 512;        // 8 waves

typedef __attribute__((ext_vector_type(8))) short short8;   // 8 bf16 (MFMA A/B frag)
typedef __attribute__((ext_vector_type(4))) float f32x4;    // MFMA C/D frag

__device__ __forceinline__ unsigned short f2bf_rne(float x) {
  union { float f; unsigned int u; } a; a.f = x;
  unsigned int r = a.u + 0x7fffu + ((a.u >> 16) & 1u);
  return (unsigned short)(r >> 16);
}

// Truncation split: hi = top 16 bits (exact bf16), lo = (x - hi) truncated to bf16.
__device__ __forceinline__ void split_pair(float x0, float x1,
                                           unsigned int& hi, unsigned int& lo) {
  unsigned int u0 = __float_as_uint(x0), u1 = __float_as_uint(x1);
  unsigned int h0 = u0 & 0xffff0000u, h1 = u1 & 0xffff0000u;
  float l0 = x0 - __uint_as_float(h0);
  float l1 = x1 - __uint_as_float(h1);
  hi = h1 | (u0 >> 16);
  lo = (__float_as_uint(l1) & 0xffff0000u) | (__float_as_uint(l0) >> 16);
}

// 8 consecutive floats (a then b) -> 8 bf16 hi + 8 bf16 lo, memory order.
__device__ __forceinline__ void split8(const float4 a, const float4 b,
                                       short8& hi, short8& lo) {
  union { unsigned int u[4]; short8 s; } H, L;
  split_pair(a.x, a.y, H.u[0], L.u[0]);
  split_pair(a.z, a.w, H.u[1], L.u[1]);
  split_pair(b.x, b.y, H.u[2], L.u[2]);
  split_pair(b.z, b.w, H.u[3], L.u[3]);
  hi = H.s; lo = L.s;
}

#define MFMA(A, B, C) __builtin_amdgcn_mfma_f32_16x16x32_bf16((A), (B), (C), 0, 0, 0)

// R4 base (TM=32, dbuf LDS, one __syncthreads per tile, 1-deep z prefetch) plus:
//  - head-pair x m-half wave split: wave w covers heads {2(w>>1), 2(w>>1)+1} on
//    tile rows [16*(w&1), 16*(w&1)+16). Each wave reads only 8 KB of the tile
//    -> block ds_read traffic halves (the LDS pipe was the loaded resource).
//    Two waves share each head's softmax; merged in the epilogue (flash-merge).
//  - defer-max online softmax (T13): common path has NO cross-lane reduce —
//    per-lane partial sum/O, e = exp(s - mrun) bounded by e^8; rare rescale
//    gated by __any(s > mrun+8) (ballot, no LDS traffic).
// Transposed MFMA: MFMA(W_frag, z_frag) = (z@W)^T, C row = d, col = m.
__global__ __launch_bounds__(NT, 2) void fused_mixedscore_attn(
    const float* __restrict__ q, const float* __restrict__ kk,
    const float* __restrict__ v, const float* __restrict__ z,
    const float* __restrict__ W1, const float* __restrict__ W2,
    float* __restrict__ out)
{
  const int n = blockIdx.x;
  const int b = blockIdx.y;
  const int tid = threadIdx.x;
  const int lane = tid & 63;
  const int wave = tid >> 6;
  const int g = wave >> 1;        // head-pair group 0..3
  const int half = wave & 1;      // m-half of the tile
  const int h0 = g * 2;
  const int col = lane & 15;      // C col = m-offset within 16-group
  const int quad = lane >> 4;     // C row-group = d-group
  const int row = half * 16 + col; // tile-local m-row of this lane's fragments

  __shared__ unsigned short zh[2][TM * CE];   // hi bf16, dbuf, 16 KB
  __shared__ unsigned short zl[2][TM * CE];   // lo bf16, dbuf, 16 KB

  const float* gz = z + (size_t)(b * CN + n) * CN * CE;

  // staging: thread handles row sr, 8 consecutive floats starting at scf
  const int sr = tid >> 4;          // 0..31
  const int scf = (tid & 15) * 8;   // 0..120
  const int wb = sr * 256 + ((scf * 2) ^ ((sr & 7) << 4));

  // ---- issue tile-0 loads first (latency hides under W/q setup) ----
  float4 zr0, zr1;
  {
    const float* g0 = gz + sr * CE + scf;
    zr0 = *(const float4*)(g0);
    zr1 = *(const float4*)(g0 + 4);
  }

  // ---- W1,W2 -> bf16 RNE fragments for this wave's two heads ----
  short8 B1[2][4], B2[2][4];   // [head][ks]
#pragma unroll
  for (int ct = 0; ct < 2; ++ct) {
    const int c = (h0 + ct) * CD + col;
#pragma unroll
    for (int ks = 0; ks < 4; ++ks) {
      union { unsigned int u[4]; short8 s; } U1, U2;
#pragma unroll
      for (int jp = 0; jp < 4; ++jp) {
        const int e = ks * 32 + quad * 8 + jp * 2;
        const float a0 = W1[(size_t)e * CHD + c];
        const float a1 = W1[(size_t)(e + 1) * CHD + c];
        const float w0 = W2[(size_t)e * CHD + c];
        const float w1 = W2[(size_t)(e + 1) * CHD + c];
        U1.u[jp] = (unsigned int)f2bf_rne(a0) | ((unsigned int)f2bf_rne(a1) << 16);
        U2.u[jp] = (unsigned int)f2bf_rne(w0) | ((unsigned int)f2bf_rne(w1) << 16);
      }
      B1[ct][ks] = U1.s;
      B2[ct][ks] = U2.s;
    }
  }

  // q for (n, h0+ct): lane needs d = quad*4..+3
  float4 qv[2];
  qv[0] = *(const float4*)&q[((size_t)(b * CH + h0) * CN + n) * CD + quad * 4];
  qv[1] = *(const float4*)&q[((size_t)(b * CH + h0 + 1) * CN + n) * CD + quad * 4];

  // defer-max state: mrun wave-uniform; srl/Oa are PER-LANE partials
  f32x4 Oa[2] = {f32x4{0.f, 0.f, 0.f, 0.f}, f32x4{0.f, 0.f, 0.f, 0.f}};
  float mrun[2] = {-3.0e38f, -3.0e38f};
  float srl[2] = {0.f, 0.f};

  const float* kb0 = kk + ((size_t)(b * CH + h0) * CN) * CD + quad * 4;
  const float* kb1 = kk + ((size_t)(b * CH + h0 + 1) * CN) * CD + quad * 4;
  const float* vb0 = v + ((size_t)(b * CH + h0) * CN) * CD + quad * 4;
  const float* vb1 = v + ((size_t)(b * CH + h0 + 1) * CN) * CD + quad * 4;

  for (int t = 0; t < NTILE; ++t) {
    const int cb = t & 1;
    const int m0 = t * TM;

    // ---- cooperative split: fp32 regs -> bf16 hi/lo LDS (512 threads) ----
    {
      short8 h8, l8;
      split8(zr0, zr1, h8, l8);
      *(short8*)((char*)&zh[cb][0] + wb) = h8;
      *(short8*)((char*)&zl[cb][0] + wb) = l8;
    }
    __syncthreads();   // single barrier per tile; dbuf makes 1-phase skew safe

    // ---- issue tile t+1 loads; they fly under the whole compute phase ----
    if (t + 1 < NTILE) {
      const float* g1 = gz + ((size_t)(t + 1) * TM + sr) * CE + scf;
      zr0 = *(const float4*)(g1);
      zr1 = *(const float4*)(g1 + 4);
    }

    // k/v for this wave's rows (m = m0+row), per head; land under MFMA section
    const size_t mo = (size_t)(m0 + row) * CD;
    const float4 k40 = *(const float4*)&kb0[mo];
    const float4 k41 = *(const float4*)&kb1[mo];
    const float4 v40 = *(const float4*)&vb0[mo];
    const float4 v41 = *(const float4*)&vb1[mo];

    // ---- transposed split-bf16 MFMA: acc[d][m] = (z@W)^T, 2 heads, 1 m-half ----
    f32x4 acc1[2], acc2[2];
#pragma unroll
    for (int ct = 0; ct < 2; ++ct) {
      acc1[ct] = f32x4{0.f, 0.f, 0.f, 0.f};
      acc2[ct] = f32x4{0.f, 0.f, 0.f, 0.f};
    }

    const char* zhb = (const char*)&zh[cb][0];
    const char* zlb = (const char*)&zl[cb][0];
#pragma unroll
    for (int ks = 0; ks < 4; ++ks) {
      const int off = row * 256 + ((ks * 64 + quad * 16) ^ ((row & 7) << 4));
      const short8 ah = *(const short8*)(zhb + off);
      const short8 al = *(const short8*)(zlb + off);
      acc1[0] = MFMA(B1[0][ks], ah, acc1[0]);
      acc1[1] = MFMA(B1[1][ks], ah, acc1[1]);
      acc2[0] = MFMA(B2[0][ks], ah, acc2[0]);
      acc2[1] = MFMA(B2[1][ks], ah, acc2[1]);
      acc1[0] = MFMA(B1[0][ks], al, acc1[0]);
      acc1[1] = MFMA(B1[1][ks], al, acc1[1]);
      acc2[0] = MFMA(B2[0][ks], al, acc2[0]);
      acc2[1] = MFMA(B2[1][ks], al, acc2[1]);
    }

    // ---- scores + defer-max softmax + PV, per head ----
#pragma unroll
    for (int ct = 0; ct < 2; ++ct) {
      const float4 k4 = ct ? k41 : k40;
      const float4 v4 = ct ? v41 : v40;
      float p = (qv[ct].x + acc1[ct][0]) * (k4.x + acc2[ct][0]);
      p += (qv[ct].y + acc1[ct][1]) * (k4.y + acc2[ct][1]);
      p += (qv[ct].z + acc1[ct][2]) * (k4.z + acc2[ct][2]);
      p += (qv[ct].w + acc1[ct][3]) * (k4.w + acc2[ct][3]);
      p += __shfl_xor(p, 16);
      p += __shfl_xor(p, 32);
      const float s = p * 0.25f;   // replicated across the 4 quads

      // rare rescale path: gated by ballot (no LDS); common path reduce-free
      if (__any(s > mrun[ct] + 8.0f)) {
        float tmax = s;
        tmax = fmaxf(tmax, __shfl_xor(tmax, 1));
        tmax = fmaxf(tmax, __shfl_xor(tmax, 2));
        tmax = fmaxf(tmax, __shfl_xor(tmax, 4));
        tmax = fmaxf(tmax, __shfl_xor(tmax, 8));
        const float mnew = fmaxf(mrun[ct], tmax);
        const float alpha = __expf(mrun[ct] - mnew);
        srl[ct] *= alpha;
        Oa[ct][0] *= alpha;
        Oa[ct][1] *= alpha;
        Oa[ct][2] *= alpha;
        Oa[ct][3] *= alpha;
        mrun[ct] = mnew;
      }
      const float e = __expf(s - mrun[ct]);   // bounded by e^8
      srl[ct] += e;
      Oa[ct][0] += e * v4.x;
      Oa[ct][1] += e * v4.y;
      Oa[ct][2] += e * v4.z;
      Oa[ct][3] += e * v4.w;
    }
  }

  // ---- epilogue: lane-reduce, then flash-merge the two m-halves per head ----
  __syncthreads();   // all tile reads done before repurposing zh as scratch
  float* scratch = (float*)&zh[0][0];   // [8 heads][2 halves][20]: m, S, O[16]

#pragma unroll
  for (int ct = 0; ct < 2; ++ct) {
    float S = srl[ct];
    S += __shfl_xor(S, 1);
    S += __shfl_xor(S, 2);
    S += __shfl_xor(S, 4);
    S += __shfl_xor(S, 8);
    float o[4];
#pragma unroll
    for (int rg = 0; rg < 4; ++rg) {
      float x = Oa[ct][rg];
      x += __shfl_xor(x, 1);
      x += __shfl_xor(x, 2);
      x += __shfl_xor(x, 4);
      x += __shfl_xor(x, 8);
      o[rg] = x;
    }
    float* dst = scratch + ((h0 + ct) * 2 + half) * 20;
    if (col == 0) {
      dst[2 + quad * 4 + 0] = o[0];
      dst[2 + quad * 4 + 1] = o[1];
      dst[2 + quad * 4 + 2] = o[2];
      dst[2 + quad * 4 + 3] = o[3];
      if (quad == 0) { dst[0] = mrun[ct]; dst[1] = S; }
    }
  }
  __syncthreads();

  if (tid < CHD) {
    const int h = tid >> 4, d = tid & 15;
    const float* p0 = scratch + (h * 2 + 0) * 20;
    const float* p1 = scratch + (h * 2 + 1) * 20;
    const float m0v = p0[0], m1v = p1[0];
    const float mm = fmaxf(m0v, m1v);
    const float w0 = __expf(m0v - mm), w1 = __expf(m1v - mm);
    const float Sv = p0[1] * w0 + p1[1] * w1;
    const float Ov = p0[2 + d] * w0 + p1[2 + d] * w1;
    out[(size_t)(b * CN + n) * CHD + h * CD + d] = Ov / Sv;
  }
}

extern "C" void kernel_launch(void* const* d_in, const int* in_sizes, int n_in,
                              void* d_out, int out_size, void* d_ws, size_t ws_size,
                              hipStream_t stream) {
  const float* q  = (const float*)d_in[0];
  const float* kv = (const float*)d_in[1];
  const float* v  = (const float*)d_in[2];
  const float* z  = (const float*)d_in[3];
  const float* W1 = (const float*)d_in[4];
  const float* W2 = (const float*)d_in[5];
  float* out = (float*)d_out;
  (void)in_sizes; (void)n_in; (void)out_size; (void)d_ws; (void)ws_size;

  dim3 grid(CN, CB);
  hipLaunchKernelGGL(fused_mixedscore_attn, grid, dim3(NT), 0, stream,
                     q, kv, v, z, W1, W2, out);
}